// Round 9
// baseline (174.004 us; speedup 1.0000x reference)
//
#include <hip/hip_runtime.h>
#include <math.h>

#define SEQ  512
#define PREV 512
#define TOT  1024
#define BSZ  8
#define DIN  1024
#define NH   16
#define HD   64

typedef __bf16 bf16;
typedef __bf16 bf16x8 __attribute__((ext_vector_type(8)));
typedef float  f32x4  __attribute__((ext_vector_type(4)));
typedef float  f32x16 __attribute__((ext_vector_type(16)));
typedef unsigned int u32;
typedef u32 u32x2 __attribute__((ext_vector_type(2)));

__device__ __forceinline__ f32x4 MFMA16(bf16x8 a, bf16x8 b, f32x4 c) {
    return __builtin_amdgcn_mfma_f32_16x16x32_bf16(a, b, c, 0, 0, 0);
}
__device__ __forceinline__ f32x16 MFMA32(bf16x8 a, bf16x8 b, f32x16 c) {
    return __builtin_amdgcn_mfma_f32_32x32x16_bf16(a, b, c, 0, 0, 0);
}

#define GLOAD16(g, l) __builtin_amdgcn_global_load_lds( \
    (const __attribute__((address_space(1))) void*)(g), \
    (__attribute__((address_space(3))) void*)(l), 16, 0, 0)

__device__ __forceinline__ unsigned short bfbits(float x) {
    return __builtin_bit_cast(unsigned short, (bf16)x);
}
__device__ __forceinline__ float bf2f(u32 bits16) {
    return __builtin_bit_cast(float, bits16 << 16);
}

// ---------------------------------------------------------------------------
// merged prep: blocks [0,8192) iwm cast; [8192,9216) pos cast; rest transcast.
// ---------------------------------------------------------------------------
__global__ __launch_bounds__(256) void prep_all(
    const float* __restrict__ memory, const float* __restrict__ input_,
    const float* __restrict__ pos,
    const float* __restrict__ W_kv, const float* __restrict__ W_q,
    const float* __restrict__ W_p,  const float* __restrict__ W_out,
    bf16* __restrict__ iwm, bf16* __restrict__ posb,
    bf16* __restrict__ wkv, bf16* __restrict__ wq,
    bf16* __restrict__ wp,  bf16* __restrict__ wo)
{
    __shared__ float tile[32][33];
    const int bid = blockIdx.x;
    const int t = threadIdx.x;
    if (bid < 9216) {
        const float* src; bf16* dst; int e4;
        if (bid < 8192) {
            e4 = (bid * 256 + t) * 4;
            src = (e4 < 4194304) ? memory : input_ - 4194304;
            dst = iwm;
        } else {
            e4 = ((bid - 8192) * 256 + t) * 4;
            src = pos; dst = posb;
        }
        float4 x = *(const float4*)(src + e4);
        union { bf16 h[4]; ushort4 u4; } pk;
        pk.h[0] = (bf16)x.x; pk.h[1] = (bf16)x.y; pk.h[2] = (bf16)x.z; pk.h[3] = (bf16)x.w;
        *(ushort4*)(dst + e4) = pk.u4;
        return;
    }
    const int rem = bid - 9216;
    const int bx = rem % 160, by = rem / 160;
    const float* W; bf16* Wt; int N, bn;
    if (bx < 64)       { W = W_kv;  Wt = wkv; N = 2048; bn = bx * 32; }
    else if (bx < 96)  { W = W_q;   Wt = wq;  N = 1024; bn = (bx - 64) * 32; }
    else if (bx < 128) { W = W_p;   Wt = wp;  N = 1024; bn = (bx - 96) * 32; }
    else               { W = W_out; Wt = wo;  N = 1024; bn = (bx - 128) * 32; }
    const int bk = by * 32;
    const int r = t >> 3, c4 = (t & 7) * 4;
    float4 x = *(const float4*)(W + (size_t)(bk + r) * N + bn + c4);
    tile[r][c4 + 0] = x.x; tile[r][c4 + 1] = x.y;
    tile[r][c4 + 2] = x.z; tile[r][c4 + 3] = x.w;
    __syncthreads();
    union { bf16 h[4]; ushort4 u4; } pk;
#pragma unroll
    for (int i = 0; i < 4; ++i) pk.h[i] = (bf16)tile[c4 + i][r];
    *(ushort4*)(Wt + (size_t)(bn + r) * 1024 + bk + c4) = pk.u4;
}

// ---------------------------------------------------------------------------
// kv projection GEMM: C[8192][2048] = A @ Bt^T. 256x256 tile, 4 waves (2x2),
// wave-tile 128x128, MFMA32 (32x32x16), acc 256 VGPR, 1 wave/SIMD.
// Rationale: LDS-read-bound kernel -> maximize MFMA per ds_read_b128
// (32 reads / 128 MFMA16-equiv per K-tile vs 24/64 at 128x64 wave-tiles).
// Double-buffered burst pipeline: vmcnt(0)+barrier, issue 16 gloads, 4 phases.
// ---------------------------------------------------------------------------
__global__ __launch_bounds__(256, 1) void gemm_kv(
    const bf16* __restrict__ A, const bf16* __restrict__ Bt,
    bf16* __restrict__ C, int M, int N, int K)
{
    __shared__ __align__(16) bf16 A_s[2][256 * 64];
    __shared__ __align__(16) bf16 B_s[2][256 * 64];
    const int t = threadIdx.x;
    const int w = t >> 6, lane = t & 63;
    const int ql = lane & 31, hi2 = lane >> 5;
    const int wm = w >> 1, wn = w & 1;
    const int lin = blockIdx.y * 8 + blockIdx.x;      // 0..255
    const int xcd = lin & 7, idx = lin >> 3;
    const int bm = (xcd * 4 + (idx & 3)) * 256;
    const int bn = (idx >> 2) * 256;

    f32x16 acc[4][4];
#pragma unroll
    for (int mf = 0; mf < 4; ++mf)
#pragma unroll
        for (int nf = 0; nf < 4; ++nf) acc[mf][nf] = (f32x16){};

    const int l7 = lane & 7, l3 = lane >> 3;

    // h: 0/1 = A row-halves, 2/3 = B row-halves. 4 gloads each (256 thr).
    auto stage_half = [&](int buf, int ks, int h) {
        const bf16* __restrict__ src = (h < 2) ? A : Bt;
        const int base = (h < 2) ? bm : bn;
        const int hh = (h & 1) * 128;
        bf16* dst = (h < 2) ? &A_s[buf][0] : &B_s[buf][0];
        const int k0 = ks << 6;
#pragma unroll
        for (int g = 0; g < 4; ++g) {
            const int row = hh + g * 32 + 8 * w + l3;       // LDS row = global row offset
            const bf16* gp = src + (size_t)(base + row) * K + k0 + ((l7 ^ (row & 7)) * 8);
            GLOAD16(gp, dst + (size_t)row * 64 + l7 * 8);   // = wave base + lane*16
        }
    };

    bf16x8 af[4], bfr[4];
    auto LDA = [&](int buf, int kt) {
#pragma unroll
        for (int mf = 0; mf < 4; ++mf) {
            int row = wm * 128 + mf * 32 + ql;
            af[mf] = *(const bf16x8*)&A_s[buf][(size_t)row * 64 + (((kt * 2 + hi2) ^ (row & 7)) * 8)];
        }
    };
    auto LDB = [&](int buf, int kt) {
#pragma unroll
        for (int nf = 0; nf < 4; ++nf) {
            int row = wn * 128 + nf * 32 + ql;
            bfr[nf] = *(const bf16x8*)&B_s[buf][(size_t)row * 64 + (((kt * 2 + hi2) ^ (row & 7)) * 8)];
        }
    };

    // prologue: stage tile 0 fully into buf 0
    stage_half(0, 0, 0); stage_half(0, 0, 1); stage_half(0, 0, 2); stage_half(0, 0, 3);

    const int nk = K >> 6;
    for (int ks = 0; ks < nk; ++ks) {
        const int cur = ks & 1, nxt = cur ^ 1;
        asm volatile("s_waitcnt vmcnt(0)" ::: "memory");   // tile ks landed (issued 4 phases ago)
        __builtin_amdgcn_sched_barrier(0);
        __builtin_amdgcn_s_barrier();
        __builtin_amdgcn_sched_barrier(0);
        if (ks + 1 < nk) {                                 // burst-issue next tile
            stage_half(nxt, ks + 1, 0); stage_half(nxt, ks + 1, 1);
            stage_half(nxt, ks + 1, 2); stage_half(nxt, ks + 1, 3);
        }
#pragma unroll
        for (int kt = 0; kt < 4; ++kt) {
            LDA(cur, kt); LDB(cur, kt);
            asm volatile("s_waitcnt lgkmcnt(0)" ::: "memory");
            __builtin_amdgcn_sched_barrier(0);
            __builtin_amdgcn_s_setprio(1);
#pragma unroll
            for (int mf = 0; mf < 4; ++mf)
#pragma unroll
                for (int nf = 0; nf < 4; ++nf)
                    acc[mf][nf] = MFMA32(af[mf], bfr[nf], acc[mf][nf]);
            __builtin_amdgcn_s_setprio(0);
        }
    }

    // epilogue: C row = (r&3)+8*(r>>2)+4*hi2 (MFMA32 C-layout), col = ql
#pragma unroll
    for (int mf = 0; mf < 4; ++mf)
#pragma unroll
        for (int nf = 0; nf < 4; ++nf)
#pragma unroll
            for (int r = 0; r < 16; ++r) {
                int row = bm + wm * 128 + mf * 32 + (r & 3) + 8 * (r >> 2) + 4 * hi2;
                int col = bn + wn * 128 + nf * 32 + ql;
                C[(size_t)row * N + col] = (bf16)acc[mf][nf][r];
            }
}

// ---------------------------------------------------------------------------
// out projection GEMM 128x128 (f32 out = acc + residual), double-buffered
// burst pipeline (grid = 256 = 1 block/CU -> staging latency otherwise exposed).
// ---------------------------------------------------------------------------
__global__ __launch_bounds__(256) void gemm_out(
    const bf16* __restrict__ A, const bf16* __restrict__ Bt,
    const float* __restrict__ Rres, float* __restrict__ Cf, int N, int K)
{
    __shared__ __align__(16) bf16 A_s[2][128 * 64];
    __shared__ __align__(16) bf16 B_s[2][128 * 64];
    const int t = threadIdx.x;
    const int w = t >> 6, lane = t & 63;
    const int li = lane & 15, hi = lane >> 4;
    const int wr = w >> 1, wc = w & 1;
    const int bm = blockIdx.y * 128, bn = blockIdx.x * 128;
    const int l3 = lane >> 3, l7 = lane & 7;
    const int srcoct = ((l7 ^ l3) * 8);

    f32x4 acc[4][4];
#pragma unroll
    for (int m = 0; m < 4; ++m)
#pragma unroll
        for (int n = 0; n < 4; ++n) acc[m][n] = (f32x4){0.f, 0.f, 0.f, 0.f};

    auto stage = [&](int buf, int k0) {
#pragma unroll
        for (int i = 0; i < 4; ++i) {
            int c = w * 4 + i;
            GLOAD16(A + (size_t)(bm + c * 8 + l3) * K + k0 + srcoct, &A_s[buf][c * 512]);
            GLOAD16(Bt + (size_t)(bn + c * 8 + l3) * K + k0 + srcoct, &B_s[buf][c * 512]);
        }
    };

    stage(0, 0);
    const int nk = K >> 6;
    for (int ks = 0; ks < nk; ++ks) {
        const int cur = ks & 1, nxt = cur ^ 1;
        asm volatile("s_waitcnt vmcnt(0)" ::: "memory");
        __builtin_amdgcn_sched_barrier(0);
        __builtin_amdgcn_s_barrier();
        __builtin_amdgcn_sched_barrier(0);
        if (ks + 1 < nk) stage(nxt, (ks + 1) << 6);
#pragma unroll
        for (int kk = 0; kk < 2; ++kk) {
            bf16x8 af[4], bfr[4];
#pragma unroll
            for (int m = 0; m < 4; ++m) {
                int row = wr * 64 + m * 16 + li;
                af[m] = *(const bf16x8*)&A_s[cur][row * 64 + ((kk * 32 + hi * 8) ^ ((row & 7) * 8))];
            }
#pragma unroll
            for (int n = 0; n < 4; ++n) {
                int row = wc * 64 + n * 16 + li;
                bfr[n] = *(const bf16x8*)&B_s[cur][row * 64 + ((kk * 32 + hi * 8) ^ ((row & 7) * 8))];
            }
            asm volatile("s_waitcnt lgkmcnt(0)" ::: "memory");
            __builtin_amdgcn_sched_barrier(0);
            __builtin_amdgcn_s_setprio(1);
#pragma unroll
            for (int m = 0; m < 4; ++m)
#pragma unroll
                for (int n = 0; n < 4; ++n)
                    acc[m][n] = MFMA16(af[m], bfr[n], acc[m][n]);
            __builtin_amdgcn_s_setprio(0);
        }
    }

#pragma unroll
    for (int m = 0; m < 4; ++m)
#pragma unroll
        for (int n = 0; n < 4; ++n)
#pragma unroll
            for (int r = 0; r < 4; ++r) {
                int row = bm + wr * 64 + m * 16 + hi * 4 + r;
                int col = bn + wc * 64 + n * 16 + li;
                size_t off = (size_t)row * N + col;
                Cf[off] = acc[m][n][r] + Rres[off];
            }
}

// ---------------------------------------------------------------------------
// merged q + p projections (bf16 out), N=K=1024. by<32: q, else p. (m97 frame)
// ---------------------------------------------------------------------------
__global__ __launch_bounds__(256) void gemm_qp(
    const bf16* __restrict__ iwmq, const bf16* __restrict__ posb,
    const bf16* __restrict__ wq, const bf16* __restrict__ wp,
    bf16* __restrict__ qbf, bf16* __restrict__ pbf)
{
    __shared__ __align__(16) bf16 A_s[128 * 64];
    __shared__ __align__(16) bf16 B_s[128 * 64];
    const int t = threadIdx.x;
    const int w = t >> 6, lane = t & 63;
    const int li = lane & 15, hi = lane >> 4;
    const int wr = w >> 1, wc = w & 1;
    const int by = blockIdx.y;
    const bf16* A; const bf16* Bt; bf16* Cb; int bm;
    if (by < 32) { A = iwmq; Bt = wq; Cb = qbf; bm = by * 128; }
    else         { A = posb; Bt = wp; Cb = pbf; bm = (by - 32) * 128; }
    const int bn = blockIdx.x * 128;
    const int l3 = lane >> 3, l7 = lane & 7;
    const int srcoct = ((l7 ^ l3) * 8);

    f32x4 acc[4][4];
#pragma unroll
    for (int m = 0; m < 4; ++m)
#pragma unroll
        for (int n = 0; n < 4; ++n) acc[m][n] = (f32x4){0.f, 0.f, 0.f, 0.f};

    auto stage = [&](int k0) {
#pragma unroll
        for (int i = 0; i < 4; ++i) {
            int c = w * 4 + i;
            GLOAD16(A + (size_t)(bm + c * 8 + l3) * 1024 + k0 + srcoct, &A_s[c * 512]);
            GLOAD16(Bt + (size_t)(bn + c * 8 + l3) * 1024 + k0 + srcoct, &B_s[c * 512]);
        }
    };

    stage(0);
    for (int ks = 0; ks < 16; ++ks) {
        __syncthreads();
#pragma unroll
        for (int kk = 0; kk < 2; ++kk) {
            bf16x8 af[4], bfr[4];
#pragma unroll
            for (int m = 0; m < 4; ++m) {
                int row = wr * 64 + m * 16 + li;
                af[m] = *(const bf16x8*)&A_s[row * 64 + ((kk * 32 + hi * 8) ^ ((row & 7) * 8))];
            }
#pragma unroll
            for (int n = 0; n < 4; ++n) {
                int row = wc * 64 + n * 16 + li;
                bfr[n] = *(const bf16x8*)&B_s[row * 64 + ((kk * 32 + hi * 8) ^ ((row & 7) * 8))];
            }
#pragma unroll
            for (int m = 0; m < 4; ++m)
#pragma unroll
                for (int n = 0; n < 4; ++n)
                    acc[m][n] = MFMA16(af[m], bfr[n], acc[m][n]);
        }
        __syncthreads();
        if (ks + 1 < 16) stage((ks + 1) << 6);
    }

#pragma unroll
    for (int m = 0; m < 4; ++m)
#pragma unroll
        for (int n = 0; n < 4; ++n)
#pragma unroll
            for (int r = 0; r < 4; ++r) {
                int row = bm + wr * 64 + m * 16 + hi * 4 + r;
                int col = bn + wc * 64 + n * 16 + li;
                Cb[(size_t)row * 1024 + col] = (bf16)acc[m][n][r];
            }
}

// ---------------------------------------------------------------------------
// Fused flash attention (Transformer-XL rel-pos), bf16 MFMA 32x32x16.
// (unchanged from R8; permlane semantics: swap(dst,src) puts the OTHER
// half's value in src for lanes<32 and in dst for lanes>=32 — epilogue
// broadcasts read lanes<32 which carry correct totals.)
// ---------------------------------------------------------------------------
__global__ __launch_bounds__(256, 2) void attn_mfma(
    const bf16* __restrict__ kv, const bf16* __restrict__ qb,
    const bf16* __restrict__ pb, const float* __restrict__ u,
    const float* __restrict__ v, bf16* __restrict__ awv)
{
    const int bi = (blockIdx.z & 1) ? (3 - blockIdx.x) : blockIdx.x;
    const int i0 = bi * 128;
    const int b  = blockIdx.y;
    const int h  = blockIdx.z;
    const int t  = threadIdx.x;
    const int w  = t >> 6;
    const int lane = t & 63;
    const int ql  = lane & 31;
    const int hi2 = lane >> 5;

    __shared__ __align__(16) bf16 K_s[64 * 64];
    __shared__ __align__(16) bf16 V_s[64][72];
    __shared__ __align__(16) bf16 P_s[256 * 64];
    __shared__ __align__(16) char SCR[4][6912];

    char* rsc = SCR[w];

    const int c8 = t & 7;
    const int rq = t >> 3;
    const int nt = 2 * bi + 10;
    const int C0 = 384 - i0;

    bf16x8 vreg[2];
#pragma unroll
    for (int p = 0; p < 2; ++p)
        vreg[p] = *(const bf16x8*)(kv + (size_t)((p * 32 + rq) * BSZ + b) * 2048 + 1024 + h * HD + c8 * 8);
#pragma unroll
    for (int p = 0; p < 2; ++p)
        GLOAD16(kv + (size_t)((p * 32 + rq) * BSZ + b) * 2048 + h * HD + ((c8 ^ (rq & 7)) * 8),
                K_s + (p * 32 + rq) * 64 + c8 * 8);
#pragma unroll
    for (int cp = 0; cp < 6; ++cp) {
        int grow = C0 + cp * 32 + rq;
        GLOAD16(pb + (size_t)grow * DIN + h * HD + ((c8 ^ (rq & 7)) * 8),
                P_s + (grow & 255) * 64 + c8 * 8);
    }

    bf16x8 qu[4], qv[4];
    {
        const size_t qoff = ((size_t)(i0 + w * 32 + ql) * BSZ + b) * DIN + h * HD;
#pragma unroll
        for (int kk = 0; kk < 4; ++kk) {
            bf16x8 q8 = *(const bf16x8*)(qb + qoff + kk * 16 + hi2 * 8);
            const float* up = u + h * HD + kk * 16 + hi2 * 8;
            const float* vp = v + h * HD + kk * 16 + hi2 * 8;
#pragma unroll
            for (int m = 0; m < 8; ++m) {
                float qf = (float)q8[m];
                qu[kk][m] = (bf16)(qf + up[m]);
                qv[kk][m] = (bf16)(qf + vp[m]);
            }
        }
    }

    float mrun = -1e30f, lrun = 0.f;
    f32x16 o[2];
    o[0] = (f32x16){}; o[1] = (f32x16){};

    const int phq = (31 - ql) & 3;
    const int sel = phq >> 1;
    const int shb = (phq & 1) * 16;

    for (int tt = 0; tt < nt; ++tt) {
        const int j0 = tt * 64;

        __builtin_amdgcn_s_barrier();                 // A
        __builtin_amdgcn_sched_barrier(0);

#pragma unroll
        for (int p = 0; p < 2; ++p) {
            int j = p * 32 + rq;
#pragma unroll
            for (int mm = 0; mm < 8; ++mm)
                V_s[c8 * 8 + mm][(j + 8 * c8) & 63] = vreg[p][mm];
        }
        asm volatile("s_waitcnt vmcnt(0) lgkmcnt(0)" ::: "memory");
        __builtin_amdgcn_sched_barrier(0);
        __builtin_amdgcn_s_barrier();                 // B
        __builtin_amdgcn_sched_barrier(0);

        f32x16 st[2];
        st[0] = (f32x16){}; st[1] = (f32x16){};
        __builtin_amdgcn_s_setprio(1);
#pragma unroll
        for (int jt = 0; jt < 2; ++jt) {
            int row = jt * 32 + ql;
#pragma unroll
            for (int kk = 0; kk < 4; ++kk) {
                bf16x8 kf = *(const bf16x8*)&K_s[row * 64 + (((kk * 2 + hi2) ^ (ql & 7)) * 8)];
                st[jt] = MFMA32(kf, qu[kk], st[jt]);
            }
        }
        const int bwg = j0 - i0 + 480 - 32 * w;
        f32x16 rp[3];
        rp[0] = (f32x16){}; rp[1] = (f32x16){}; rp[2] = (f32x16){};
#pragma unroll
        for (int Rt = 0; Rt < 3; ++Rt) {
            int ring = (bwg + Rt * 32 + ql) & 255;
#pragma unroll
            for (int kk = 0; kk < 4; ++kk) {
                bf16x8 pf = *(const bf16x8*)&P_s[ring * 64 + (((kk * 2 + hi2) ^ (ring & 7)) * 8)];
                rp[Rt] = MFMA32(pf, qv[kk], rp[Rt]);
            }
        }
        __builtin_amdgcn_s_setprio(0);

#pragma unroll
        for (int Rt = 0; Rt < 3; ++Rt)
#pragma unroll
            for (int a = 0; a < 4; ++a) {
                u32 lo = (u32)bfbits(rp[Rt][a * 4 + 0]) | ((u32)bfbits(rp[Rt][a * 4 + 1]) << 16);
                u32 hi = (u32)bfbits(rp[Rt][a * 4 + 2]) | ((u32)bfbits(rp[Rt][a * 4 + 3]) << 16);
                *(u32x2*)(rsc + ql * 216 + 64 * Rt + 16 * a + 8 * hi2) = (u32x2){lo, hi};
            }

        __builtin_amdgcn_s_barrier();                 // C
        __builtin_amdgcn_sched_barrier(0);

        if (tt + 1 < nt) {
            const int j0n = j0 + 64;
#pragma unroll
            for (int p = 0; p < 2; ++p)
                vreg[p] = *(const bf16x8*)(kv + (size_t)((j0n + p * 32 + rq) * BSZ + b) * 2048 + 1024 + h * HD + c8 * 8);
#pragma unroll
            for (int p = 0; p < 2; ++p)
                GLOAD16(kv + (size_t)((j0n + p * 32 + rq) * BSZ + b) * 2048 + h * HD + ((c8 ^ (rq & 7)) * 8),
                        K_s + (p * 32 + rq) * 64 + c8 * 8);
        }
        if (tt + 3 < nt) {
            const int Cs = C0 + (tt + 3) * 64;
#pragma unroll
            for (int p = 0; p < 2; ++p) {
                int grow = Cs + p * 32 + rq;
                GLOAD16(pb + (size_t)grow * DIN + h * HD + ((c8 ^ (rq & 7)) * 8),
                        P_s + (grow & 255) * 64 + c8 * 8);
            }
        }

        float rowmax = -1e30f;
        const int limb = i0 + 32 * w + ql + PREV - j0;
        auto assemble = [&](bool domask) {
#pragma unroll
            for (int jt = 0; jt < 2; ++jt)
#pragma unroll
                for (int a = 0; a < 4; ++a) {
                    int e = jt * 32 + 8 * a + 4 * hi2 + 31 - ql;
                    const u32x2* W = (const u32x2*)(rsc + ql * 216 + 8 * (e >> 2));
                    u32x2 A0 = W[0], A1 = W[1];
                    u32 U0 = sel ? A0[1] : A0[0];
                    u32 U1 = sel ? A1[0] : A0[1];
                    u32 U2 = sel ? A1[1] : A1[0];
                    u32 o0 = (u32)((((unsigned long long)U1 << 32) | U0) >> shb);
                    u32 o1 = (u32)((((unsigned long long)U2 << 32) | U1) >> shb);
                    float pq[4] = {bf2f(o0 & 0xffffu), bf2f(o0 >> 16),
                                   bf2f(o1 & 0xffffu), bf2f(o1 >> 16)};
#pragma unroll
                    for (int rr = 0; rr < 4; ++rr) {
                        int r = a * 4 + rr;
                        int lj = jt * 32 + 8 * a + 4 * hi2 + rr;
                        float sv = (st[jt][r] + pq[rr]) * 0.125f;
                        if (domask && lj > limb) sv = -1e30f;
                        st[jt][r] = sv;
                        rowmax = fmaxf(rowmax, sv);
                    }
                }
        };
        if (__builtin_amdgcn_readfirstlane(j0 + 63 - (i0 + 32 * w + PREV)) > 0)
            assemble(true);
        else
            assemble(false);

        {
            u32 rm = __builtin_bit_cast(u32, rowmax), rm2 = rm;
            asm("v_permlane32_swap_b32 %0, %1" : "+v"(rm), "+v"(rm2));
            rowmax = fmaxf(rowmax, __builtin_bit_cast(float, rm));
            rowmax = fmaxf(rowmax, __builtin_bit_cast(float, rm2));
        }

        if (!__all(rowmax - mrun <= 8.f)) {
            float newm = fmaxf(mrun, rowmax);
            float fsc = __expf(mrun - newm);
#pragma unroll
            for (int r = 0; r < 16; ++r) {
                float fr = __shfl(fsc, (r & 3) + 8 * (r >> 2) + 4 * hi2);
                o[0][r] *= fr; o[1][r] *= fr;
            }
            lrun *= fsc;
            mrun = newm;
        }
        float rowsum = 0.f;
#pragma unroll
        for (int jt = 0; jt < 2; ++jt)
#pragma unroll
            for (int r = 0; r < 16; ++r) {
                float p = __expf(st[jt][r] - mrun);
                st[jt][r] = p;
                rowsum += p;
            }
        {
            u32 rs = __builtin_bit_cast(u32, rowsum), rs2 = rs;
            asm("v_permlane32_swap_b32 %0, %1" : "+v"(rs), "+v"(rs2));
            rowsum += __builtin_bit_cast(float, rs2);
        }
        lrun += rowsum;

        u32 pk0[2][4], pk1[2][4];
#pragma unroll
        for (int jt = 0; jt < 2; ++jt)
#pragma unroll
            for (int a = 0; a < 4; ++a) {
                pk0[jt][a] = (u32)bfbits(st[jt][a * 4 + 0]) | ((u32)bfbits(st[jt][a * 4 + 1]) << 16);
                pk1[jt][a] = (u32)bfbits(st[jt][a * 4 + 2]) | ((u32)bfbits(st[jt][a * 4 + 3]) << 16);
            }

        __builtin_amdgcn_s_setprio(1);
#pragma unroll
        for (int js = 0; js < 4; ++js) {
            const int jt = js >> 1, a0 = 2 * (js & 1), a1 = a0 + 1;
            u32 w0 = pk0[jt][a0], w2 = pk0[jt][a1];
            asm("v_permlane32_swap_b32 %0, %1" : "+v"(w0), "+v"(w2));
            u32 w1 = pk1[jt][a0], w3 = pk1[jt][a1];
            asm("v_permlane32_swap_b32 %0, %1" : "+v"(w1), "+v"(w3));
            union { u32 uw[4]; bf16x8 vv; } pa;
            pa.uw[0] = w0; pa.uw[1] = w1; pa.uw[2] = w2; pa.uw[3] = w3;
#pragma unroll
            for (int dt = 0; dt < 2; ++dt) {
                int dcol = dt * 32 + ql;
                int colb = (js * 16 + hi2 * 8 + 8 * (dcol >> 3)) & 63;
                bf16x8 vf = *(const bf16x8*)&V_s[dcol][colb];
                o[dt] = MFMA32(pa.vv, vf, o[dt]);
            }
        }
        __builtin_amdgcn_s_setprio(0);
    }

    float linv = __builtin_amdgcn_rcpf(lrun);
    float lr[16];
#pragma unroll
    for (int r = 0; r < 16; ++r) lr[r] = __shfl(linv, (r & 3) + 8 * (r >> 2) + 4 * hi2);
#pragma unroll
    for (int dt = 0; dt < 2; ++dt)
#pragma unroll
        for (int r = 0; r < 16; ++r) {
            int row = i0 + 32 * w + (r & 3) + 8 * (r >> 2) + 4 * hi2;
            awv[((size_t)row * BSZ + b) * DIN + h * HD + dt * 32 + ql] = (bf16)(o[dt][r] * lr[r]);
        }
}

// ---------------------------------------------------------------------------
// In-place LayerNorm over last dim (1024). One block per row.
// ---------------------------------------------------------------------------
__global__ __launch_bounds__(256) void ln_f32(
    float* __restrict__ out, const float* __restrict__ gamma, const float* __restrict__ beta)
{
    const int row = blockIdx.x;
    const int t = threadIdx.x;
    float4 x = *(float4*)(out + (size_t)row * DIN + t * 4);
    float s  = x.x + x.y + x.z + x.w;
    float ss = x.x * x.x + x.y * x.y + x.z * x.z + x.w * x.w;
#pragma unroll
    for (int wd = 1; wd < 64; wd <<= 1) { s += __shfl_xor(s, wd); ss += __shfl_xor(ss, wd); }
    __shared__ float sbuf[4], ssbuf[4];
    const int wave = t >> 6, lanei = t & 63;
    if (lanei == 0) { sbuf[wave] = s; ssbuf[wave] = ss; }
    __syncthreads();
    s  = sbuf[0] + sbuf[1] + sbuf[2] + sbuf[3];
    ss = ssbuf[0] + ssbuf[1] + ssbuf[2] + ssbuf[3];
    const float mu   = s * (1.f / DIN);
    const float var  = ss * (1.f / DIN) - mu * mu;
    const float rstd = rsqrtf(var + 1e-5f);
    float4 g  = *(const float4*)(gamma + t * 4);
    float4 bb = *(const float4*)(beta + t * 4);
    float4 y;
    y.x = (x.x - mu) * rstd * g.x + bb.x;
    y.y = (x.y - mu) * rstd * g.y + bb.y;
    y.z = (x.z - mu) * rstd * g.z + bb.z;
    y.w = (x.w - mu) * rstd * g.w + bb.w;
    *(float4*)(out + (size_t)row * DIN + t * 4) = y;
}

// ---------------------------------------------------------------------------
extern "C" void kernel_launch(void* const* d_in, const int* in_sizes, int n_in,
                              void* d_out, int out_size, void* d_ws, size_t ws_size,
                              hipStream_t stream)
{
    const float* input_ = (const float*)d_in[0];
    const float* pos    = (const float*)d_in[1];
    const float* memory = (const float*)d_in[2];
    const float* u      = (const float*)d_in[3];
    const float* v      = (const float*)d_in[4];
    // d_in[5] = mask: computed analytically (j > i + PREV)
    const float* W_kv   = (const float*)d_in[6];
    const float* W_q    = (const float*)d_in[7];
    const float* W_p    = (const float*)d_in[8];
    const float* W_out  = (const float*)d_in[9];
    const float* gamma  = (const float*)d_in[10];
    const float* beta   = (const float*)d_in[11];

    bf16* iwm  = (bf16*)d_ws;                      // [8192][1024]
    bf16* kvb  = iwm  + (size_t)8192 * 1024;       // [8192][2048]
    bf16* qbf  = kvb  + (size_t)8192 * 2048;       // [4096][1024]
    bf16* pbf  = qbf  + (size_t)4096 * 1024;       // [1024][1024]
    bf16* posb = pbf  + (size_t)1024 * 1024;       // [1024][1024]
    bf16* wkv  = posb + (size_t)1024 * 1024;       // [2048][1024]
    bf16* wq   = wkv  + (size_t)2048 * 1024;
    bf16* wp   = wq   + (size_t)1024 * 1024;
    bf16* wo   = wp   + (size_t)1024 * 1024;
    bf16* awvb = wo   + (size_t)1024 * 1024;       // [4096][1024]
    float* outf = (float*)d_out;

    prep_all<<<14336, 256, 0, stream>>>(memory, input_, pos, W_kv, W_q, W_p, W_out,
                                        iwm, posb, wkv, wq, wp, wo);

    gemm_kv<<<dim3(8, 32), 256, 0, stream>>>(iwm, wkv, kvb, 8192, 2048, 1024);
    gemm_qp<<<dim3(8, 40), 256, 0, stream>>>(iwm + (size_t)4096 * 1024, posb, wq, wp, qbf, pbf);

    attn_mfma<<<dim3(4, 8, 16), 256, 0, stream>>>(kvb, qbf, pbf, u, v, awvb);

    gemm_out<<<dim3(8, 32), 256, 0, stream>>>(awvb, wo, input_, outf, 1024, 1024);
    ln_f32<<<4096, 256, 0, stream>>>(outf, gamma, beta);
}

// Round 10
// 170.020 us; speedup vs baseline: 1.0234x; 1.0234x over previous
//
#include <hip/hip_runtime.h>
#include <math.h>

#define SEQ  512
#define PREV 512
#define TOT  1024
#define BSZ  8
#define DIN  1024
#define NH   16
#define HD   64

typedef __bf16 bf16;
typedef __bf16 bf16x8 __attribute__((ext_vector_type(8)));
typedef float  f32x4  __attribute__((ext_vector_type(4)));
typedef float  f32x16 __attribute__((ext_vector_type(16)));
typedef unsigned int u32;
typedef u32 u32x2 __attribute__((ext_vector_type(2)));

__device__ __forceinline__ f32x4 MFMA16(bf16x8 a, bf16x8 b, f32x4 c) {
    return __builtin_amdgcn_mfma_f32_16x16x32_bf16(a, b, c, 0, 0, 0);
}
__device__ __forceinline__ f32x16 MFMA32(bf16x8 a, bf16x8 b, f32x16 c) {
    return __builtin_amdgcn_mfma_f32_32x32x16_bf16(a, b, c, 0, 0, 0);
}

#define GLOAD16(g, l) __builtin_amdgcn_global_load_lds( \
    (const __attribute__((address_space(1))) void*)(g), \
    (__attribute__((address_space(3))) void*)(l), 16, 0, 0)

__device__ __forceinline__ unsigned short bfbits(float x) {
    return __builtin_bit_cast(unsigned short, (bf16)x);
}
__device__ __forceinline__ float bf2f(u32 bits16) {
    return __builtin_bit_cast(float, bits16 << 16);
}
__device__ __forceinline__ float exp2_raw(float x) {   // raw v_exp_f32 (= 2^x)
    float r;
    asm("v_exp_f32 %0, %1" : "=v"(r) : "v"(x));
    return r;
}

// ---------------------------------------------------------------------------
// merged prep: blocks [0,8192) iwm cast; [8192,9216) pos cast; rest transcast.
// ---------------------------------------------------------------------------
__global__ __launch_bounds__(256) void prep_all(
    const float* __restrict__ memory, const float* __restrict__ input_,
    const float* __restrict__ pos,
    const float* __restrict__ W_kv, const float* __restrict__ W_q,
    const float* __restrict__ W_p,  const float* __restrict__ W_out,
    bf16* __restrict__ iwm, bf16* __restrict__ posb,
    bf16* __restrict__ wkv, bf16* __restrict__ wq,
    bf16* __restrict__ wp,  bf16* __restrict__ wo)
{
    __shared__ float tile[32][33];
    const int bid = blockIdx.x;
    const int t = threadIdx.x;
    if (bid < 9216) {
        const float* src; bf16* dst; int e4;
        if (bid < 8192) {
            e4 = (bid * 256 + t) * 4;
            src = (e4 < 4194304) ? memory : input_ - 4194304;
            dst = iwm;
        } else {
            e4 = ((bid - 8192) * 256 + t) * 4;
            src = pos; dst = posb;
        }
        float4 x = *(const float4*)(src + e4);
        union { bf16 h[4]; ushort4 u4; } pk;
        pk.h[0] = (bf16)x.x; pk.h[1] = (bf16)x.y; pk.h[2] = (bf16)x.z; pk.h[3] = (bf16)x.w;
        *(ushort4*)(dst + e4) = pk.u4;
        return;
    }
    const int rem = bid - 9216;
    const int bx = rem % 160, by = rem / 160;
    const float* W; bf16* Wt; int N, bn;
    if (bx < 64)       { W = W_kv;  Wt = wkv; N = 2048; bn = bx * 32; }
    else if (bx < 96)  { W = W_q;   Wt = wq;  N = 1024; bn = (bx - 64) * 32; }
    else if (bx < 128) { W = W_p;   Wt = wp;  N = 1024; bn = (bx - 96) * 32; }
    else               { W = W_out; Wt = wo;  N = 1024; bn = (bx - 128) * 32; }
    const int bk = by * 32;
    const int r = t >> 3, c4 = (t & 7) * 4;
    float4 x = *(const float4*)(W + (size_t)(bk + r) * N + bn + c4);
    tile[r][c4 + 0] = x.x; tile[r][c4 + 1] = x.y;
    tile[r][c4 + 2] = x.z; tile[r][c4 + 3] = x.w;
    __syncthreads();
    union { bf16 h[4]; ushort4 u4; } pk;
#pragma unroll
    for (int i = 0; i < 4; ++i) pk.h[i] = (bf16)tile[c4 + i][r];
    *(ushort4*)(Wt + (size_t)(bn + r) * 1024 + bk + c4) = pk.u4;
}

// ---------------------------------------------------------------------------
// kv projection GEMM: C[8192][2048] = A @ Bt^T. 256x256 tile, 4 waves (2x2),
// wave-tile 128x128, MFMA32. R10: register-level frag double-buffer —
// issue kt+1's 8 ds_read_b128 BEFORE kt's MFMA cluster, wait lgkmcnt(8);
// LDS reads hide under the 16-MFMA32 (~128cy) matrix cluster (1 wave/SIMD).
// ---------------------------------------------------------------------------
__global__ __launch_bounds__(256, 1) void gemm_kv(
    const bf16* __restrict__ A, const bf16* __restrict__ Bt,
    bf16* __restrict__ C, int M, int N, int K)
{
    __shared__ __align__(16) bf16 A_s[2][256 * 64];
    __shared__ __align__(16) bf16 B_s[2][256 * 64];
    const int t = threadIdx.x;
    const int w = t >> 6, lane = t & 63;
    const int ql = lane & 31, hi2 = lane >> 5;
    const int wm = w >> 1, wn = w & 1;
    const int lin = blockIdx.y * 8 + blockIdx.x;      // 0..255
    const int xcd = lin & 7, idx = lin >> 3;
    const int bm = (xcd * 4 + (idx & 3)) * 256;
    const int bn = (idx >> 2) * 256;

    f32x16 acc[4][4];
#pragma unroll
    for (int mf = 0; mf < 4; ++mf)
#pragma unroll
        for (int nf = 0; nf < 4; ++nf) acc[mf][nf] = (f32x16){};

    const int l7 = lane & 7, l3 = lane >> 3;

    auto stage_half = [&](int buf, int ks, int h) {
        const bf16* __restrict__ src = (h < 2) ? A : Bt;
        const int base = (h < 2) ? bm : bn;
        const int hh = (h & 1) * 128;
        bf16* dst = (h < 2) ? &A_s[buf][0] : &B_s[buf][0];
        const int k0 = ks << 6;
#pragma unroll
        for (int g = 0; g < 4; ++g) {
            const int row = hh + g * 32 + 8 * w + l3;
            const bf16* gp = src + (size_t)(base + row) * K + k0 + ((l7 ^ (row & 7)) * 8);
            GLOAD16(gp, dst + (size_t)row * 64 + l7 * 8);
        }
    };

    bf16x8 af[2][4], bfr[2][4];
    auto LDA = [&](int buf, int kt, int set) {
#pragma unroll
        for (int mf = 0; mf < 4; ++mf) {
            int row = wm * 128 + mf * 32 + ql;
            af[set][mf] = *(const bf16x8*)&A_s[buf][(size_t)row * 64 + (((kt * 2 + hi2) ^ (row & 7)) * 8)];
        }
    };
    auto LDB = [&](int buf, int kt, int set) {
#pragma unroll
        for (int nf = 0; nf < 4; ++nf) {
            int row = wn * 128 + nf * 32 + ql;
            bfr[set][nf] = *(const bf16x8*)&B_s[buf][(size_t)row * 64 + (((kt * 2 + hi2) ^ (row & 7)) * 8)];
        }
    };

    // prologue: stage tile 0 fully into buf 0
    stage_half(0, 0, 0); stage_half(0, 0, 1); stage_half(0, 0, 2); stage_half(0, 0, 3);

    const int nk = K >> 6;
    for (int ks = 0; ks < nk; ++ks) {
        const int cur = ks & 1, nxt = cur ^ 1;
        asm volatile("s_waitcnt vmcnt(0)" ::: "memory");   // tile ks landed (issued 1 tile ago)
        __builtin_amdgcn_sched_barrier(0);
        __builtin_amdgcn_s_barrier();
        __builtin_amdgcn_sched_barrier(0);
        LDA(cur, 0, 0); LDB(cur, 0, 0);                    // kt0 frag reads first
        if (ks + 1 < nk) {                                 // burst-issue next tile (vmcnt side)
            stage_half(nxt, ks + 1, 0); stage_half(nxt, ks + 1, 1);
            stage_half(nxt, ks + 1, 2); stage_half(nxt, ks + 1, 3);
        }
#pragma unroll
        for (int kt = 0; kt < 4; ++kt) {
            const int set = kt & 1;
            if (kt < 3) {                                  // prefetch kt+1 frags, then wait kt's 8
                LDA(cur, kt + 1, set ^ 1); LDB(cur, kt + 1, set ^ 1);
                asm volatile("s_waitcnt lgkmcnt(8)" ::: "memory");
            } else {
                asm volatile("s_waitcnt lgkmcnt(0)" ::: "memory");
            }
            __builtin_amdgcn_sched_barrier(0);
            __builtin_amdgcn_s_setprio(1);
#pragma unroll
            for (int mf = 0; mf < 4; ++mf)
#pragma unroll
                for (int nf = 0; nf < 4; ++nf)
                    acc[mf][nf] = MFMA32(af[set][mf], bfr[set][nf], acc[mf][nf]);
            __builtin_amdgcn_s_setprio(0);
        }
    }

    // epilogue: C row = (r&3)+8*(r>>2)+4*hi2 (MFMA32 C-layout), col = ql
#pragma unroll
    for (int mf = 0; mf < 4; ++mf)
#pragma unroll
        for (int nf = 0; nf < 4; ++nf)
#pragma unroll
            for (int r = 0; r < 16; ++r) {
                int row = bm + wm * 128 + mf * 32 + (r & 3) + 8 * (r >> 2) + 4 * hi2;
                int col = bn + wn * 128 + nf * 32 + ql;
                C[(size_t)row * N + col] = (bf16)acc[mf][nf][r];
            }
}

// ---------------------------------------------------------------------------
// out projection GEMM 128x128 (f32 out = acc + residual), double-buffered.
// ---------------------------------------------------------------------------
__global__ __launch_bounds__(256) void gemm_out(
    const bf16* __restrict__ A, const bf16* __restrict__ Bt,
    const float* __restrict__ Rres, float* __restrict__ Cf, int N, int K)
{
    __shared__ __align__(16) bf16 A_s[2][128 * 64];
    __shared__ __align__(16) bf16 B_s[2][128 * 64];
    const int t = threadIdx.x;
    const int w = t >> 6, lane = t & 63;
    const int li = lane & 15, hi = lane >> 4;
    const int wr = w >> 1, wc = w & 1;
    const int bm = blockIdx.y * 128, bn = blockIdx.x * 128;
    const int l3 = lane >> 3, l7 = lane & 7;
    const int srcoct = ((l7 ^ l3) * 8);

    f32x4 acc[4][4];
#pragma unroll
    for (int m = 0; m < 4; ++m)
#pragma unroll
        for (int n = 0; n < 4; ++n) acc[m][n] = (f32x4){0.f, 0.f, 0.f, 0.f};

    auto stage = [&](int buf, int k0) {
#pragma unroll
        for (int i = 0; i < 4; ++i) {
            int c = w * 4 + i;
            GLOAD16(A + (size_t)(bm + c * 8 + l3) * K + k0 + srcoct, &A_s[buf][c * 512]);
            GLOAD16(Bt + (size_t)(bn + c * 8 + l3) * K + k0 + srcoct, &B_s[buf][c * 512]);
        }
    };

    stage(0, 0);
    const int nk = K >> 6;
    for (int ks = 0; ks < nk; ++ks) {
        const int cur = ks & 1, nxt = cur ^ 1;
        asm volatile("s_waitcnt vmcnt(0)" ::: "memory");
        __builtin_amdgcn_sched_barrier(0);
        __builtin_amdgcn_s_barrier();
        __builtin_amdgcn_sched_barrier(0);
        if (ks + 1 < nk) stage(nxt, (ks + 1) << 6);
#pragma unroll
        for (int kk = 0; kk < 2; ++kk) {
            bf16x8 af[4], bfr[4];
#pragma unroll
            for (int m = 0; m < 4; ++m) {
                int row = wr * 64 + m * 16 + li;
                af[m] = *(const bf16x8*)&A_s[cur][row * 64 + ((kk * 32 + hi * 8) ^ ((row & 7) * 8))];
            }
#pragma unroll
            for (int n = 0; n < 4; ++n) {
                int row = wc * 64 + n * 16 + li;
                bfr[n] = *(const bf16x8*)&B_s[cur][row * 64 + ((kk * 32 + hi * 8) ^ ((row & 7) * 8))];
            }
            asm volatile("s_waitcnt lgkmcnt(0)" ::: "memory");
            __builtin_amdgcn_sched_barrier(0);
            __builtin_amdgcn_s_setprio(1);
#pragma unroll
            for (int m = 0; m < 4; ++m)
#pragma unroll
                for (int n = 0; n < 4; ++n)
                    acc[m][n] = MFMA16(af[m], bfr[n], acc[m][n]);
            __builtin_amdgcn_s_setprio(0);
        }
    }

#pragma unroll
    for (int m = 0; m < 4; ++m)
#pragma unroll
        for (int n = 0; n < 4; ++n)
#pragma unroll
            for (int r = 0; r < 4; ++r) {
                int row = bm + wr * 64 + m * 16 + hi * 4 + r;
                int col = bn + wc * 64 + n * 16 + li;
                size_t off = (size_t)row * N + col;
                Cf[off] = acc[m][n][r] + Rres[off];
            }
}

// ---------------------------------------------------------------------------
// merged q + p projections (bf16 out), N=K=1024. by<32: q, else p.
// ---------------------------------------------------------------------------
__global__ __launch_bounds__(256) void gemm_qp(
    const bf16* __restrict__ iwmq, const bf16* __restrict__ posb,
    const bf16* __restrict__ wq, const bf16* __restrict__ wp,
    bf16* __restrict__ qbf, bf16* __restrict__ pbf)
{
    __shared__ __align__(16) bf16 A_s[128 * 64];
    __shared__ __align__(16) bf16 B_s[128 * 64];
    const int t = threadIdx.x;
    const int w = t >> 6, lane = t & 63;
    const int li = lane & 15, hi = lane >> 4;
    const int wr = w >> 1, wc = w & 1;
    const int by = blockIdx.y;
    const bf16* A; const bf16* Bt; bf16* Cb; int bm;
    if (by < 32) { A = iwmq; Bt = wq; Cb = qbf; bm = by * 128; }
    else         { A = posb; Bt = wp; Cb = pbf; bm = (by - 32) * 128; }
    const int bn = blockIdx.x * 128;
    const int l3 = lane >> 3, l7 = lane & 7;
    const int srcoct = ((l7 ^ l3) * 8);

    f32x4 acc[4][4];
#pragma unroll
    for (int m = 0; m < 4; ++m)
#pragma unroll
        for (int n = 0; n < 4; ++n) acc[m][n] = (f32x4){0.f, 0.f, 0.f, 0.f};

    auto stage = [&](int k0) {
#pragma unroll
        for (int i = 0; i < 4; ++i) {
            int c = w * 4 + i;
            GLOAD16(A + (size_t)(bm + c * 8 + l3) * 1024 + k0 + srcoct, &A_s[c * 512]);
            GLOAD16(Bt + (size_t)(bn + c * 8 + l3) * 1024 + k0 + srcoct, &B_s[c * 512]);
        }
    };

    stage(0);
    for (int ks = 0; ks < 16; ++ks) {
        __syncthreads();
#pragma unroll
        for (int kk = 0; kk < 2; ++kk) {
            bf16x8 af[4], bfr[4];
#pragma unroll
            for (int m = 0; m < 4; ++m) {
                int row = wr * 64 + m * 16 + li;
                af[m] = *(const bf16x8*)&A_s[row * 64 + ((kk * 32 + hi * 8) ^ ((row & 7) * 8))];
            }
#pragma unroll
            for (int n = 0; n < 4; ++n) {
                int row = wc * 64 + n * 16 + li;
                bfr[n] = *(const bf16x8*)&B_s[row * 64 + ((kk * 32 + hi * 8) ^ ((row & 7) * 8))];
            }
#pragma unroll
            for (int m = 0; m < 4; ++m)
#pragma unroll
                for (int n = 0; n < 4; ++n)
                    acc[m][n] = MFMA16(af[m], bfr[n], acc[m][n]);
        }
        __syncthreads();
        if (ks + 1 < 16) stage((ks + 1) << 6);
    }

#pragma unroll
    for (int m = 0; m < 4; ++m)
#pragma unroll
        for (int n = 0; n < 4; ++n)
#pragma unroll
            for (int r = 0; r < 4; ++r) {
                int row = bm + wr * 64 + m * 16 + hi * 4 + r;
                int col = bn + wc * 64 + n * 16 + li;
                Cb[(size_t)row * 1024 + col] = (bf16)acc[m][n][r];
            }
}

// ---------------------------------------------------------------------------
// Fused flash attention (Transformer-XL rel-pos), bf16 MFMA 32x32x16.
// R10: exp2-domain softmax via raw v_exp_f32 (scale folded with log2e).
// ---------------------------------------------------------------------------
__global__ __launch_bounds__(256, 2) void attn_mfma(
    const bf16* __restrict__ kv, const bf16* __restrict__ qb,
    const bf16* __restrict__ pb, const float* __restrict__ u,
    const float* __restrict__ v, bf16* __restrict__ awv)
{
    const int bi = (blockIdx.z & 1) ? (3 - blockIdx.x) : blockIdx.x;
    const int i0 = bi * 128;
    const int b  = blockIdx.y;
    const int h  = blockIdx.z;
    const int t  = threadIdx.x;
    const int w  = t >> 6;
    const int lane = t & 63;
    const int ql  = lane & 31;
    const int hi2 = lane >> 5;

    __shared__ __align__(16) bf16 K_s[64 * 64];
    __shared__ __align__(16) bf16 V_s[64][72];
    __shared__ __align__(16) bf16 P_s[256 * 64];
    __shared__ __align__(16) char SCR[4][6912];

    char* rsc = SCR[w];

    const int c8 = t & 7;
    const int rq = t >> 3;
    const int nt = 2 * bi + 10;
    const int C0 = 384 - i0;
    const float SCL2 = 0.125f * 1.44269504088896f;   // scale * log2(e)

    bf16x8 vreg[2];
#pragma unroll
    for (int p = 0; p < 2; ++p)
        vreg[p] = *(const bf16x8*)(kv + (size_t)((p * 32 + rq) * BSZ + b) * 2048 + 1024 + h * HD + c8 * 8);
#pragma unroll
    for (int p = 0; p < 2; ++p)
        GLOAD16(kv + (size_t)((p * 32 + rq) * BSZ + b) * 2048 + h * HD + ((c8 ^ (rq & 7)) * 8),
                K_s + (p * 32 + rq) * 64 + c8 * 8);
#pragma unroll
    for (int cp = 0; cp < 6; ++cp) {
        int grow = C0 + cp * 32 + rq;
        GLOAD16(pb + (size_t)grow * DIN + h * HD + ((c8 ^ (rq & 7)) * 8),
                P_s + (grow & 255) * 64 + c8 * 8);
    }

    bf16x8 qu[4], qv[4];
    {
        const size_t qoff = ((size_t)(i0 + w * 32 + ql) * BSZ + b) * DIN + h * HD;
#pragma unroll
        for (int kk = 0; kk < 4; ++kk) {
            bf16x8 q8 = *(const bf16x8*)(qb + qoff + kk * 16 + hi2 * 8);
            const float* up = u + h * HD + kk * 16 + hi2 * 8;
            const float* vp = v + h * HD + kk * 16 + hi2 * 8;
#pragma unroll
            for (int m = 0; m < 8; ++m) {
                float qf = (float)q8[m];
                qu[kk][m] = (bf16)(qf + up[m]);
                qv[kk][m] = (bf16)(qf + vp[m]);
            }
        }
    }

    float mrun = -1e30f, lrun = 0.f;
    f32x16 o[2];
    o[0] = (f32x16){}; o[1] = (f32x16){};

    const int phq = (31 - ql) & 3;
    const int sel = phq >> 1;
    const int shb = (phq & 1) * 16;

    for (int tt = 0; tt < nt; ++tt) {
        const int j0 = tt * 64;

        __builtin_amdgcn_s_barrier();                 // A
        __builtin_amdgcn_sched_barrier(0);

#pragma unroll
        for (int p = 0; p < 2; ++p) {
            int j = p * 32 + rq;
#pragma unroll
            for (int mm = 0; mm < 8; ++mm)
                V_s[c8 * 8 + mm][(j + 8 * c8) & 63] = vreg[p][mm];
        }
        asm volatile("s_waitcnt vmcnt(0) lgkmcnt(0)" ::: "memory");
        __builtin_amdgcn_sched_barrier(0);
        __builtin_amdgcn_s_barrier();                 // B
        __builtin_amdgcn_sched_barrier(0);

        f32x16 st[2];
        st[0] = (f32x16){}; st[1] = (f32x16){};
        __builtin_amdgcn_s_setprio(1);
#pragma unroll
        for (int jt = 0; jt < 2; ++jt) {
            int row = jt * 32 + ql;
#pragma unroll
            for (int kk = 0; kk < 4; ++kk) {
                bf16x8 kf = *(const bf16x8*)&K_s[row * 64 + (((kk * 2 + hi2) ^ (ql & 7)) * 8)];
                st[jt] = MFMA32(kf, qu[kk], st[jt]);
            }
        }
        const int bwg = j0 - i0 + 480 - 32 * w;
        f32x16 rp[3];
        rp[0] = (f32x16){}; rp[1] = (f32x16){}; rp[2] = (f32x16){};
#pragma unroll
        for (int Rt = 0; Rt < 3; ++Rt) {
            int ring = (bwg + Rt * 32 + ql) & 255;
#pragma unroll
            for (int kk = 0; kk < 4; ++kk) {
                bf16x8 pf = *(const bf16x8*)&P_s[ring * 64 + (((kk * 2 + hi2) ^ (ring & 7)) * 8)];
                rp[Rt] = MFMA32(pf, qv[kk], rp[Rt]);
            }
        }
        __builtin_amdgcn_s_setprio(0);

#pragma unroll
        for (int Rt = 0; Rt < 3; ++Rt)
#pragma unroll
            for (int a = 0; a < 4; ++a) {
                u32 lo = (u32)bfbits(rp[Rt][a * 4 + 0]) | ((u32)bfbits(rp[Rt][a * 4 + 1]) << 16);
                u32 hi = (u32)bfbits(rp[Rt][a * 4 + 2]) | ((u32)bfbits(rp[Rt][a * 4 + 3]) << 16);
                *(u32x2*)(rsc + ql * 216 + 64 * Rt + 16 * a + 8 * hi2) = (u32x2){lo, hi};
            }

        __builtin_amdgcn_s_barrier();                 // C
        __builtin_amdgcn_sched_barrier(0);

        if (tt + 1 < nt) {
            const int j0n = j0 + 64;
#pragma unroll
            for (int p = 0; p < 2; ++p)
                vreg[p] = *(const bf16x8*)(kv + (size_t)((j0n + p * 32 + rq) * BSZ + b) * 2048 + 1024 + h * HD + c8 * 8);
#pragma unroll
            for (int p = 0; p < 2; ++p)
                GLOAD16(kv + (size_t)((j0n + p * 32 + rq) * BSZ + b) * 2048 + h * HD + ((c8 ^ (rq & 7)) * 8),
                        K_s + (p * 32 + rq) * 64 + c8 * 8);
        }
        if (tt + 3 < nt) {
            const int Cs = C0 + (tt + 3) * 64;
#pragma unroll
            for (int p = 0; p < 2; ++p) {
                int grow = Cs + p * 32 + rq;
                GLOAD16(pb + (size_t)grow * DIN + h * HD + ((c8 ^ (rq & 7)) * 8),
                        P_s + (grow & 255) * 64 + c8 * 8);
            }
        }

        float rowmax = -1e30f;
        const int limb = i0 + 32 * w + ql + PREV - j0;
        auto assemble = [&](bool domask) {
#pragma unroll
            for (int jt = 0; jt < 2; ++jt)
#pragma unroll
                for (int a = 0; a < 4; ++a) {
                    int e = jt * 32 + 8 * a + 4 * hi2 + 31 - ql;
                    const u32x2* W = (const u32x2*)(rsc + ql * 216 + 8 * (e >> 2));
                    u32x2 A0 = W[0], A1 = W[1];
                    u32 U0 = sel ? A0[1] : A0[0];
                    u32 U1 = sel ? A1[0] : A0[1];
                    u32 U2 = sel ? A1[1] : A1[0];
                    u32 o0 = (u32)((((unsigned long long)U1 << 32) | U0) >> shb);
                    u32 o1 = (u32)((((unsigned long long)U2 << 32) | U1) >> shb);
                    float pq[4] = {bf2f(o0 & 0xffffu), bf2f(o0 >> 16),
                                   bf2f(o1 & 0xffffu), bf2f(o1 >> 16)};
#pragma unroll
                    for (int rr = 0; rr < 4; ++rr) {
                        int r = a * 4 + rr;
                        int lj = jt * 32 + 8 * a + 4 * hi2 + rr;
                        float sv = (st[jt][r] + pq[rr]) * SCL2;   // log2-domain logits
                        if (domask && lj > limb) sv = -1e30f;
                        st[jt][r] = sv;
                        rowmax = fmaxf(rowmax, sv);
                    }
                }
        };
        if (__builtin_amdgcn_readfirstlane(j0 + 63 - (i0 + 32 * w + PREV)) > 0)
            assemble(true);
        else
            assemble(false);

        {
            u32 rm = __builtin_bit_cast(u32, rowmax), rm2 = rm;
            asm("v_permlane32_swap_b32 %0, %1" : "+v"(rm), "+v"(rm2));
            rowmax = fmaxf(rowmax, __builtin_bit_cast(float, rm));
            rowmax = fmaxf(rowmax, __builtin_bit_cast(float, rm2));
        }

        if (!__all(rowmax - mrun <= 11.54f)) {        // 8 nats in log2 units
            float newm = fmaxf(mrun, rowmax);
            float fsc = exp2_raw(mrun - newm);
#pragma unroll
            for (int r = 0; r < 16; ++r) {
                float fr = __shfl(fsc, (r & 3) + 8 * (r >> 2) + 4 * hi2);
                o[0][r] *= fr; o[1][r] *= fr;
            }
            lrun *= fsc;
            mrun = newm;
        }
        float rowsum = 0.f;
#pragma unroll
        for (int jt = 0; jt < 2; ++jt)
#pragma unroll
            for (int r = 0; r < 16; ++r) {
                float p = exp2_raw(st[jt][r] - mrun);
                st[jt][r] = p;
                rowsum += p;
            }
        {
            u32 rs = __builtin_bit_cast(u32, rowsum), rs2 = rs;
            asm("v_permlane32_swap_b32 %0, %1" : "+v"(rs), "+v"(rs2));
            rowsum += __builtin_bit_cast(float, rs2);
        }
        lrun += rowsum;

        u32 pk0[2][4], pk1[2][4];
#pragma unroll
        for (int jt = 0; jt < 2; ++jt)
#pragma unroll
            for (int a = 0; a < 4; ++a) {
                pk0[jt][a] = (u32)bfbits(st[jt][a * 4 + 0]) | ((u32)bfbits(st[jt][a * 4 + 1]) << 16);
                pk1[jt][a] = (u32)bfbits(st[jt][a * 4 + 2]) | ((u32)bfbits(st[jt][a * 4 + 3]) << 16);
            }

        __builtin_amdgcn_s_setprio(1);
#pragma unroll
        for (int js = 0; js < 4; ++js) {
            const int jt = js >> 1, a0 = 2 * (js & 1), a1 = a0 + 1;
            u32 w0 = pk0[jt][a0], w2 = pk0[jt][a1];
            asm("v_permlane32_swap_b32 %0, %1" : "+v"(w0), "+v"(w2));
            u32 w1 = pk1[jt][a0], w3 = pk1[jt][a1];
            asm("v_permlane32_swap_b32 %0, %1" : "+v"(w1), "+v"(w3));
            union { u32 uw[4]; bf16x8 vv; } pa;
            pa.uw[0] = w0; pa.uw[1] = w1; pa.uw[2] = w2; pa.uw[3] = w3;
#pragma unroll
            for (int dt = 0; dt < 2; ++dt) {
                int dcol = dt * 32 + ql;
                int colb = (js * 16 + hi2 * 8 + 8 * (dcol >> 3)) & 63;
                bf16x8 vf = *(const bf16x8*)&V_s[dcol][colb];
                o[dt] = MFMA32(pa.vv, vf, o[dt]);
            }
        }
        __builtin_amdgcn_s_setprio(0);
    }

    float linv = __builtin_amdgcn_rcpf(lrun);
    float lr[16];
#pragma unroll
    for (int r = 0; r < 16; ++r) lr[r] = __shfl(linv, (r & 3) + 8 * (r >> 2) + 4 * hi2);
#pragma unroll
    for (int dt = 0; dt < 2; ++dt)
#pragma unroll
        for (int r = 0; r < 16; ++r) {
            int row = i0 + 32 * w + (r & 3) + 8 * (r >> 2) + 4 * hi2;
            awv[((size_t)row * BSZ + b) * DIN + h * HD + dt * 32 + ql] = (bf16)(o[dt][r] * lr[r]);
        }
}

// ---------------------------------------------------------------------------
// In-place LayerNorm over last dim (1024). One block per row.
// ---------------------------------------------------------------------------
__global__ __launch_bounds__(256) void ln_f32(
    float* __restrict__ out, const float* __restrict__ gamma, const float* __restrict__ beta)
{
    const int row = blockIdx.x;
    const int t = threadIdx.x;
    float4 x = *(float4*)(out + (size_t)row * DIN + t * 4);
    float s  = x.x + x.y + x.z + x.w;
    float ss = x.x * x.x + x.y * x.y + x.z * x.z + x.w * x.w;
#pragma unroll
    for (int wd = 1; wd < 64; wd <<= 1) { s += __shfl_xor(s, wd); ss += __shfl_xor(ss, wd); }
    __shared__ float sbuf[4], ssbuf[4];
    const int wave = t >> 6, lanei = t & 63;
    if (lanei == 0) { sbuf[wave] = s; ssbuf[wave] = ss; }
    __syncthreads();
    s  = sbuf[0] + sbuf[1] + sbuf[2] + sbuf[3];
    ss = ssbuf[0] + ssbuf[1] + ssbuf[2] + ssbuf[3];
    const float mu   = s * (1.f / DIN);
    const float var  = ss * (1.f / DIN) - mu * mu;
    const float rstd = rsqrtf(var + 1e-5f);
    float4 g  = *(const float4*)(gamma + t * 4);
    float4 bb = *(const float4*)(beta + t * 4);
    float4 y;
    y.x = (x.x - mu) * rstd * g.x + bb.x;
    y.y = (x.y - mu) * rstd * g.y + bb.y;
    y.z = (x.z - mu) * rstd * g.z + bb.z;
    y.w = (x.w - mu) * rstd * g.w + bb.w;
    *(float4*)(out + (size_t)row * DIN + t * 4) = y;
}

// ---------------------------------------------------------------------------
extern "C" void kernel_launch(void* const* d_in, const int* in_sizes, int n_in,
                              void* d_out, int out_size, void* d_ws, size_t ws_size,
                              hipStream_t stream)
{
    const float* input_ = (const float*)d_in[0];
    const float* pos    = (const float*)d_in[1];
    const float* memory = (const float*)d_in[2];
    const float* u      = (const float*)d_in[3];
    const float* v      = (const float*)d_in[4];
    // d_in[5] = mask: computed analytically (j > i + PREV)
    const float* W_kv   = (const float*)d_in[6];
    const float* W_q    = (const float*)d_in[7];
    const float* W_p    = (const float*)d_in[8];
    const float* W_out  = (const float*)d_in[9];
    const float* gamma  = (const float*)d_in[10];
    const float* beta   = (const float*)d_in[11];

    bf16* iwm  = (bf16*)d_ws;                      // [8192][1024]
    bf16* kvb  = iwm  + (size_t)8192 * 1024;       // [8192][2048]
    bf16* qbf  = kvb  + (size_t)8192 * 2048;       // [4096][1024]
    bf16* pbf  = qbf  + (size_t)4096 * 1024;       // [1024][1024]
    bf16* posb = pbf  + (size_t)1024 * 1024;       // [1024][1024]
    bf16* wkv  = posb + (size_t)1024 * 1024;       // [2048][1024]
    bf16* wq   = wkv  + (size_t)2048 * 1024;
    bf16* wp   = wq   + (size_t)1024 * 1024;
    bf16* wo   = wp   + (size_t)1024 * 1024;
    bf16* awvb = wo   + (size_t)1024 * 1024;       // [4096][1024]
    float* outf = (float*)d_out;

    prep_all<<<14336, 256, 0, stream>>>(memory, input_, pos, W_kv, W_q, W_p, W_out,
                                        iwm, posb, wkv, wq, wp, wo);

    gemm_kv<<<dim3(8, 32), 256, 0, stream>>>(iwm, wkv, kvb, 8192, 2048, 1024);
    gemm_qp<<<dim3(8, 40), 256, 0, stream>>>(iwm + (size_t)4096 * 1024, posb, wq, wp, qbf, pbf);

    attn_mfma<<<dim3(4, 8, 16), 256, 0, stream>>>(kvb, qbf, pbf, u, v, awvb);

    gemm_out<<<dim3(8, 32), 256, 0, stream>>>(awvb, wo, input_, outf, 1024, 1024);
    ln_f32<<<4096, 256, 0, stream>>>(outf, gamma, beta);
}